// Round 16
// baseline (73.104 us; speedup 1.0000x reference)
//
#include <hip/hip_runtime.h>
#include <hip/hip_bf16.h>

#define B_ 2
#define N_ 2048
#define FIN 512
#define H_ 8
#define DH 64
#define HD 512 /* H_*DH */
#define SLOPE 0.2f
#define LOG2E 1.44269504088896340736f

typedef __attribute__((ext_vector_type(8))) short short8;
typedef __attribute__((ext_vector_type(4))) float f32x4;
typedef unsigned short ushort_t;

__device__ __forceinline__ ushort_t hi_trunc(float x) {
  return (ushort_t)(__float_as_uint(x) >> 16);
}
__device__ __forceinline__ ushort_t lo_part(float x) {
  const float hf = __uint_as_float(__float_as_uint(x) & 0xFFFF0000u);
  const __hip_bfloat16 lb = __float2bfloat16(x - hf);
  return *(const ushort_t*)&lb;
}
__device__ __forceinline__ ushort_t bf16_rne(float x) {
  const __hip_bfloat16 b = __float2bfloat16(x);
  return *(const ushort_t*)&b;
}

// K1: g = f @ W via bf16 MFMA split precision. BM=128, BN=64, BK=64, 512 thr.
// Epilogue: (a) LDS-bounce transpose -> gThi/gTlo[bh][d][n]; (b) fused sl/sr
// plus precomputed Bn = exp(sr), Dn = exp(0.2*sr) for the attn factorization.
__global__ __launch_bounds__(512) void k_gemm_fused(
    const float* __restrict__ f, const float* __restrict__ W,
    const float* __restrict__ aw, ushort_t* __restrict__ gThi,
    ushort_t* __restrict__ gTlo, float* __restrict__ sl,
    float* __restrict__ sr, float* __restrict__ Bn, float* __restrict__ Dn) {
  __shared__ ushort_t lA[2][2][128 * 64];  // 64KB; reused as fp32 T[64][132]
  __shared__ ushort_t lB[2][2][64 * 64];   // 32KB
  __shared__ float slp[2][128], srp[2][128];
  const int tid = threadIdx.x;
  const int lane = tid & 63;
  const int wave = tid >> 6;
  const int row0 = blockIdx.x * 128;
  const int col0 = blockIdx.y * 64;
  const int wm = (wave >> 1) * 32;
  const int wn = (wave & 1) * 32;
  const int ar = tid >> 2;
  const int aks = (tid & 3) * 16;
  const int bn = tid & 63;
  const int bks = (tid >> 6) * 8;
  f32x4 acc[2][2] = {};
  float fa[16];
  float fb[8];

#define LOADR(k0)                                                           \
  {                                                                         \
    const float* ap = f + (row0 + ar) * FIN + (k0) + aks;                   \
    _Pragma("unroll") for (int i = 0; i < 4; ++i) {                         \
      const float4 v = *(const float4*)(ap + i * 4);                        \
      fa[i * 4 + 0] = v.x; fa[i * 4 + 1] = v.y;                             \
      fa[i * 4 + 2] = v.z; fa[i * 4 + 3] = v.w;                             \
    }                                                                       \
    _Pragma("unroll") for (int j = 0; j < 8; ++j)                           \
      fb[j] = W[((k0) + bks + j) * HD + col0 + bn];                         \
  }

#define WRITELDS(buf)                                                       \
  {                                                                         \
    _Pragma("unroll") for (int c = 0; c < 2; ++c) {                         \
      short8 hv, lv;                                                        \
      _Pragma("unroll") for (int j = 0; j < 8; ++j) {                       \
        hv[j] = (short)hi_trunc(fa[c * 8 + j]);                             \
        lv[j] = (short)lo_part(fa[c * 8 + j]);                              \
      }                                                                     \
      const int kbA = ((tid & 3) << 5) + (c << 4);                          \
      const int offA = (ar * 128 + (kbA ^ ((ar & 7) << 4))) >> 1;           \
      *(short8*)&lA[buf][0][offA] = hv;                                     \
      *(short8*)&lA[buf][1][offA] = lv;                                     \
    }                                                                       \
    {                                                                       \
      short8 hv, lv;                                                        \
      _Pragma("unroll") for (int j = 0; j < 8; ++j) {                       \
        hv[j] = (short)hi_trunc(fb[j]);                                     \
        lv[j] = (short)lo_part(fb[j]);                                      \
      }                                                                     \
      const int kbB = bks << 1;                                             \
      const int offB = (bn * 128 + (kbB ^ ((bn & 7) << 4))) >> 1;           \
      *(short8*)&lB[buf][0][offB] = hv;                                     \
      *(short8*)&lB[buf][1][offB] = lv;                                     \
    }                                                                       \
  }

  LOADR(0);
  WRITELDS(0);
  __syncthreads();
  int cur = 0;
  for (int t = 0; t < 8; ++t) {
    if (t < 7) LOADR((t + 1) * 64);
#pragma unroll
    for (int kk = 0; kk < 2; ++kk) {
      short8 a_h[2], a_l[2], b_h[2], b_l[2];
      const int kbyte = kk * 64 + ((lane >> 4) << 4);
#pragma unroll
      for (int fm = 0; fm < 2; ++fm) {
        const int row = wm + fm * 16 + (lane & 15);
        const int off = (row * 128 + (kbyte ^ ((row & 7) << 4))) >> 1;
        a_h[fm] = *(const short8*)&lA[cur][0][off];
        a_l[fm] = *(const short8*)&lA[cur][1][off];
      }
#pragma unroll
      for (int fn = 0; fn < 2; ++fn) {
        const int nn = wn + fn * 16 + (lane & 15);
        const int off = (nn * 128 + (kbyte ^ ((nn & 7) << 4))) >> 1;
        b_h[fn] = *(const short8*)&lB[cur][0][off];
        b_l[fn] = *(const short8*)&lB[cur][1][off];
      }
#pragma unroll
      for (int fm = 0; fm < 2; ++fm)
#pragma unroll
        for (int fn = 0; fn < 2; ++fn) {
          acc[fm][fn] = __builtin_amdgcn_mfma_f32_16x16x32_bf16(
              a_h[fm], b_h[fn], acc[fm][fn], 0, 0, 0);
          acc[fm][fn] = __builtin_amdgcn_mfma_f32_16x16x32_bf16(
              a_h[fm], b_l[fn], acc[fm][fn], 0, 0, 0);
          acc[fm][fn] = __builtin_amdgcn_mfma_f32_16x16x32_bf16(
              a_l[fm], b_h[fn], acc[fm][fn], 0, 0, 0);
        }
    }
    if (t < 7) WRITELDS(cur ^ 1);
    __syncthreads();
    cur ^= 1;
  }
#undef LOADR
#undef WRITELDS

  // ---- epilogue A: transpose head-tile via LDS, store bf16 hi/lo gT ----
  float* T = (float*)lA;  // [64 cols][132 rows-padded]
#pragma unroll
  for (int fm = 0; fm < 2; ++fm)
#pragma unroll
    for (int fn = 0; fn < 2; ++fn)
#pragma unroll
      for (int r = 0; r < 4; ++r) {
        const int col = wn + fn * 16 + (lane & 15);
        const int rl = wm + fm * 16 + ((lane >> 4) << 2) + r;
        T[col * 132 + rl] = acc[fm][fn][r];
      }
  __syncthreads();
  {
    const int b = row0 >> 11;
    const int n0 = row0 & (N_ - 1);
    const int d = tid >> 3;
    const int nc = (tid & 7) * 16;
    const size_t gb = ((size_t)((b * H_ + blockIdx.y) * 64 + d)) * N_ + n0 + nc;
#pragma unroll
    for (int half = 0; half < 2; ++half) {
      short8 hv, lv;
#pragma unroll
      for (int u = 0; u < 8; ++u) {
        const float x = T[d * 132 + nc + half * 8 + u];
        hv[u] = (short)hi_trunc(x);
        lv[u] = (short)lo_part(x);
      }
      *(short8*)&gThi[gb + half * 8] = hv;
      *(short8*)&gTlo[gb + half * 8] = lv;
    }
  }

  // ---- epilogue B: fused sl/sr + exp-factor tables ----
  const float al0 = aw[wn + (lane & 15)];
  const float al1 = aw[wn + 16 + (lane & 15)];
  const float ar0 = aw[DH + wn + (lane & 15)];
  const float ar1 = aw[DH + wn + 16 + (lane & 15)];
#pragma unroll
  for (int fm = 0; fm < 2; ++fm)
#pragma unroll
    for (int r = 0; r < 4; ++r) {
      float vsl = acc[fm][0][r] * al0 + acc[fm][1][r] * al1;
      float vsr = acc[fm][0][r] * ar0 + acc[fm][1][r] * ar1;
#pragma unroll
      for (int off = 1; off < 16; off <<= 1) {
        vsl += __shfl_xor(vsl, off, 64);
        vsr += __shfl_xor(vsr, off, 64);
      }
      if ((lane & 15) == 0) {
        const int rr = wm + fm * 16 + ((lane >> 4) << 2) + r;
        slp[wn >> 5][rr] = vsl;
        srp[wn >> 5][rr] = vsr;
      }
    }
  __syncthreads();
  if (tid < 128) {
    const int grow = row0 + tid;
    const int b = grow >> 11, n = grow & (N_ - 1);
    const int h = blockIdx.y;
    const int idx = (b * H_ + h) * N_ + n;
    const float srv = srp[0][tid] + srp[1][tid];
    sl[idx] = slp[0][tid] + slp[1][tid];
    sr[idx] = srv;
    Bn[idx] = exp2f(srv * LOG2E);
    Dn[idx] = exp2f(srv * (SLOPE * LOG2E));
  }
}

// K2: flash attention, rank-1 scores, exact precomputed row max, and the
// exp-FACTORIZED P: P = (Bj >= Ti) ? Ai*Bj : Ci*Dj  — zero transcendentals
// in the hot loop. Z via MFMA(ones). Grid (16 bh, 64 it) x 128 thr (2 waves
// x 16 rows): 1024 blocks = 4 blocks/CU (4 indep barrier groups).
__global__ __launch_bounds__(128) void k_attn(const ushort_t* __restrict__ gThi,
                                              const ushort_t* __restrict__ gTlo,
                                              const float* __restrict__ sl,
                                              const float* __restrict__ sr,
                                              const float* __restrict__ Bn,
                                              const float* __restrict__ Dn,
                                              float* __restrict__ out) {
  __shared__ ushort_t ghi[2][64 * 64];  // 8KB per buf
  __shared__ ushort_t glo[2][64 * 64];
  __shared__ float wred[2];
  const int tid = threadIdx.x;
  const int lane = tid & 63;
  const int wave = tid >> 6;  // 0..1
  const int bh = blockIdx.x;
  const int b = bh >> 3, h = bh & 7;
  const int i0 = blockIdx.y * 32 + wave * 16;
  const int row_l = lane & 15;
  const int kg = lane >> 4;
  const int sd = tid >> 1;            // staging d 0..63 (2 thr per d-row)
  const int sjb = (tid & 1) * 32;     // staging j half

  // prologue: srmax for this bh
  float mx = -1e30f;
  for (int q = tid; q < N_; q += 128) mx = fmaxf(mx, sr[bh * N_ + q]);
#pragma unroll
  for (int off = 32; off > 0; off >>= 1) mx = fmaxf(mx, __shfl_xor(mx, off, 64));
  if (lane == 0) wred[wave] = mx;
  __syncthreads();
  mx = fmaxf(wred[0], wred[1]);

  const float sli = sl[bh * N_ + i0 + row_l];
  const float pre = sli + mx;
  const float Mi = fmaxf(pre, SLOPE * pre);      // exact row max of e
  const float Ai = exp2f(fmaf(sli, LOG2E, -Mi * LOG2E));
  const float Ci = exp2f(fmaf(sli, SLOPE * LOG2E, -Mi * LOG2E));
  const float Ti = exp2f(-sli * LOG2E);          // Bj >= Ti <=> srj >= -sli

  int ridx[4][2];
#pragma unroll
  for (int gg = 0; gg < 4; ++gg) {
    const int d = gg * 16 + row_l;
#pragma unroll
    for (int kk = 0; kk < 2; ++kk) {
      const int j0r = kk * 32 + kg * 8;
      ridx[gg][kk] = d * 64 + (j0r ^ ((d & 7) << 3));
    }
  }
  const short8 ones = {0x3F80, 0x3F80, 0x3F80, 0x3F80,
                       0x3F80, 0x3F80, 0x3F80, 0x3F80};

  const ushort_t* gH = gThi + ((size_t)bh * 64 + sd) * N_ + sjb;
  const ushort_t* gL = gTlo + ((size_t)bh * 64 + sd) * N_ + sjb;
  const float* Bp0 = Bn + bh * N_ + kg * 8;
  const float* Bp1 = Bn + bh * N_ + 32 + kg * 8;
  const float* Dp0 = Dn + bh * N_ + kg * 8;
  const float* Dp1 = Dn + bh * N_ + 32 + kg * 8;

  f32x4 O[4] = {};
  f32x4 Zacc = {};
  short8 sh0, sh1, sh2, sh3, sv0, sv1, sv2, sv3;
  float4 cb0, cb1, cb2, cb3, cd0, cd1, cd2, cd3;  // current B/D
  float4 pb0, pb1, pb2, pb3, pd0, pd1, pd2, pd3;  // prefetch

#define ALOAD(jb)                                                           \
  {                                                                         \
    sh0 = *(const short8*)&gH[jb];                                          \
    sh1 = *(const short8*)&gH[(jb) + 8];                                    \
    sh2 = *(const short8*)&gH[(jb) + 16];                                   \
    sh3 = *(const short8*)&gH[(jb) + 24];                                   \
    sv0 = *(const short8*)&gL[jb];                                          \
    sv1 = *(const short8*)&gL[(jb) + 8];                                    \
    sv2 = *(const short8*)&gL[(jb) + 16];                                   \
    sv3 = *(const short8*)&gL[(jb) + 24];                                   \
  }
#define BDLOAD(jb, B0, B1, B2, B3, D0, D1, D2, D3)                          \
  {                                                                         \
    B0 = *(const float4*)&Bp0[jb];                                          \
    B1 = *(const float4*)&Bp0[(jb) + 4];                                    \
    B2 = *(const float4*)&Bp1[jb];                                          \
    B3 = *(const float4*)&Bp1[(jb) + 4];                                    \
    D0 = *(const float4*)&Dp0[jb];                                          \
    D1 = *(const float4*)&Dp0[(jb) + 4];                                    \
    D2 = *(const float4*)&Dp1[jb];                                          \
    D3 = *(const float4*)&Dp1[(jb) + 4];                                    \
  }
#define AWRITE(buf)                                                         \
  {                                                                         \
    const int base_ = sd * 64;                                              \
    const int sw_ = (sd & 7) << 3;                                          \
    *(short8*)&ghi[buf][base_ + ((sjb + 0) ^ sw_)] = sh0;                   \
    *(short8*)&ghi[buf][base_ + ((sjb + 8) ^ sw_)] = sh1;                   \
    *(short8*)&ghi[buf][base_ + ((sjb + 16) ^ sw_)] = sh2;                  \
    *(short8*)&ghi[buf][base_ + ((sjb + 24) ^ sw_)] = sh3;                  \
    *(short8*)&glo[buf][base_ + ((sjb + 0) ^ sw_)] = sv0;                   \
    *(short8*)&glo[buf][base_ + ((sjb + 8) ^ sw_)] = sv1;                   \
    *(short8*)&glo[buf][base_ + ((sjb + 16) ^ sw_)] = sv2;                  \
    *(short8*)&glo[buf][base_ + ((sjb + 24) ^ sw_)] = sv3;                  \
  }

  ALOAD(0);
  AWRITE(0);
  BDLOAD(0, cb0, cb1, cb2, cb3, cd0, cd1, cd2, cd3);
  __syncthreads();
  int cur = 0;
  for (int t = 0; t < 32; ++t) {
    if (t < 31) {
      ALOAD((t + 1) * 64);
      BDLOAD((t + 1) * 64, pb0, pb1, pb2, pb3, pd0, pd1, pd2, pd3);
    }
    // P = sel(Bj>=Ti, Ai*Bj, Ci*Dj), bf16 — 4 cheap VALU per element
    short8 a[2];
    {
      const float bs0[8] = {cb0.x, cb0.y, cb0.z, cb0.w, cb1.x, cb1.y, cb1.z, cb1.w};
      const float ds0[8] = {cd0.x, cd0.y, cd0.z, cd0.w, cd1.x, cd1.y, cd1.z, cd1.w};
      const float bs1[8] = {cb2.x, cb2.y, cb2.z, cb2.w, cb3.x, cb3.y, cb3.z, cb3.w};
      const float ds1[8] = {cd2.x, cd2.y, cd2.z, cd2.w, cd3.x, cd3.y, cd3.z, cd3.w};
#pragma unroll
      for (int u = 0; u < 8; ++u) {
        const float p0 = (bs0[u] >= Ti) ? Ai * bs0[u] : Ci * ds0[u];
        a[0][u] = (short)bf16_rne(p0);
        const float p1 = (bs1[u] >= Ti) ? Ai * bs1[u] : Ci * ds1[u];
        a[1][u] = (short)bf16_rne(p1);
      }
    }
    Zacc = __builtin_amdgcn_mfma_f32_16x16x32_bf16(a[0], ones, Zacc, 0, 0, 0);
    Zacc = __builtin_amdgcn_mfma_f32_16x16x32_bf16(a[1], ones, Zacc, 0, 0, 0);
#pragma unroll
    for (int gg = 0; gg < 4; ++gg)
#pragma unroll
      for (int kk = 0; kk < 2; ++kk) {
        const short8 b_h = *(const short8*)&ghi[cur][ridx[gg][kk]];
        const short8 b_l = *(const short8*)&glo[cur][ridx[gg][kk]];
        O[gg] = __builtin_amdgcn_mfma_f32_16x16x32_bf16(a[kk], b_h, O[gg], 0, 0, 0);
        O[gg] = __builtin_amdgcn_mfma_f32_16x16x32_bf16(a[kk], b_l, O[gg], 0, 0, 0);
      }
    if (t < 31) {
      AWRITE(cur ^ 1);
      cb0 = pb0; cb1 = pb1; cb2 = pb2; cb3 = pb3;
      cd0 = pd0; cd1 = pd1; cd2 = pd2; cd3 = pd3;
    }
    __syncthreads();
    cur ^= 1;
  }
#undef ALOAD
#undef BDLOAD
#undef AWRITE
  // epilogue: O / Z (Zacc shares the C-fragment row layout — no shuffles)
#pragma unroll
  for (int gg = 0; gg < 4; ++gg)
#pragma unroll
    for (int rr = 0; rr < 4; ++rr) {
      const int row = i0 + kg * 4 + rr;
      const int col = h * DH + gg * 16 + row_l;
      out[(b * N_ + row) * HD + col] = O[gg][rr] / Zacc[rr];
    }
}

extern "C" void kernel_launch(void* const* d_in, const int* in_sizes, int n_in,
                              void* d_out, int out_size, void* d_ws, size_t ws_size,
                              hipStream_t stream) {
  const float* f = (const float*)d_in[0];
  // d_in[1] = adj_mat (all ones, unused by reference math)
  const float* W = (const float*)d_in[2];
  const float* aw = (const float*)d_in[3];
  float* out = (float*)d_out;

  ushort_t* gThi = (ushort_t*)d_ws;          // [16 bh][64 d][2048 n] bf16 hi
  ushort_t* gTlo = gThi + 16 * 64 * N_;      // lo
  float* sl = (float*)(gTlo + 16 * 64 * N_); // [bh][n]
  float* sr = sl + B_ * N_ * H_;
  float* Bn = sr + B_ * N_ * H_;             // exp(sr)
  float* Dn = Bn + B_ * N_ * H_;             // exp(0.2*sr)

  hipLaunchKernelGGL(k_gemm_fused, dim3((B_ * N_) / 128, HD / 64), dim3(512), 0, stream,
                     f, W, aw, gThi, gTlo, sl, sr, Bn, Dn);
  hipLaunchKernelGGL(k_attn, dim3(B_ * H_, N_ / 32), dim3(128), 0, stream,
                     gThi, gTlo, sl, sr, Bn, Dn, out);
}

// Round 17
// 47.869 us; speedup vs baseline: 1.5272x; 1.5272x over previous
//
#include <hip/hip_runtime.h>
#include <hip/hip_bf16.h>

#define B_ 2
#define N_ 2048
#define FIN 512
#define H_ 8
#define DH 64
#define HD 512 /* H_*DH */
#define SLOPE 0.2f
#define LOG2E 1.44269504088896340736f

typedef __attribute__((ext_vector_type(8))) short short8;
typedef __attribute__((ext_vector_type(4))) float f32x4;
typedef unsigned short ushort_t;

__device__ __forceinline__ ushort_t hi_trunc(float x) {
  return (ushort_t)(__float_as_uint(x) >> 16);
}
__device__ __forceinline__ ushort_t lo_part(float x) {
  const float hf = __uint_as_float(__float_as_uint(x) & 0xFFFF0000u);
  const __hip_bfloat16 lb = __float2bfloat16(x - hf);
  return *(const ushort_t*)&lb;
}
__device__ __forceinline__ ushort_t bf16_rne(float x) {
  const __hip_bfloat16 b = __float2bfloat16(x);
  return *(const ushort_t*)&b;
}

// K1: g = f @ W via bf16 MFMA split precision. BM=128, BN=64, BK=64, 512 thr.
// Epilogue: (a) LDS-bounce transpose -> gT[bh][d][n] (bf16 RNE, single);
// (b) fused sl/sr + exp tables Bn=exp(sr), Dn=exp(0.2*sr).
__global__ __launch_bounds__(512) void k_gemm_fused(
    const float* __restrict__ f, const float* __restrict__ W,
    const float* __restrict__ aw, ushort_t* __restrict__ gT,
    float* __restrict__ sl, float* __restrict__ sr,
    float* __restrict__ Bn, float* __restrict__ Dn) {
  __shared__ ushort_t lA[2][2][128 * 64];  // 64KB; reused as fp32 T[64][132]
  __shared__ ushort_t lB[2][2][64 * 64];   // 32KB
  __shared__ float slp[2][128], srp[2][128];
  const int tid = threadIdx.x;
  const int lane = tid & 63;
  const int wave = tid >> 6;
  const int row0 = blockIdx.x * 128;
  const int col0 = blockIdx.y * 64;
  const int wm = (wave >> 1) * 32;
  const int wn = (wave & 1) * 32;
  const int ar = tid >> 2;
  const int aks = (tid & 3) * 16;
  const int bn = tid & 63;
  const int bks = (tid >> 6) * 8;
  f32x4 acc[2][2] = {};
  float fa[16];
  float fb[8];

#define LOADR(k0)                                                           \
  {                                                                         \
    const float* ap = f + (row0 + ar) * FIN + (k0) + aks;                   \
    _Pragma("unroll") for (int i = 0; i < 4; ++i) {                         \
      const float4 v = *(const float4*)(ap + i * 4);                        \
      fa[i * 4 + 0] = v.x; fa[i * 4 + 1] = v.y;                             \
      fa[i * 4 + 2] = v.z; fa[i * 4 + 3] = v.w;                             \
    }                                                                       \
    _Pragma("unroll") for (int j = 0; j < 8; ++j)                           \
      fb[j] = W[((k0) + bks + j) * HD + col0 + bn];                         \
  }

#define WRITELDS(buf)                                                       \
  {                                                                         \
    _Pragma("unroll") for (int c = 0; c < 2; ++c) {                         \
      short8 hv, lv;                                                        \
      _Pragma("unroll") for (int j = 0; j < 8; ++j) {                       \
        hv[j] = (short)hi_trunc(fa[c * 8 + j]);                             \
        lv[j] = (short)lo_part(fa[c * 8 + j]);                              \
      }                                                                     \
      const int kbA = ((tid & 3) << 5) + (c << 4);                          \
      const int offA = (ar * 128 + (kbA ^ ((ar & 7) << 4))) >> 1;           \
      *(short8*)&lA[buf][0][offA] = hv;                                     \
      *(short8*)&lA[buf][1][offA] = lv;                                     \
    }                                                                       \
    {                                                                       \
      short8 hv, lv;                                                        \
      _Pragma("unroll") for (int j = 0; j < 8; ++j) {                       \
        hv[j] = (short)hi_trunc(fb[j]);                                     \
        lv[j] = (short)lo_part(fb[j]);                                      \
      }                                                                     \
      const int kbB = bks << 1;                                             \
      const int offB = (bn * 128 + (kbB ^ ((bn & 7) << 4))) >> 1;           \
      *(short8*)&lB[buf][0][offB] = hv;                                     \
      *(short8*)&lB[buf][1][offB] = lv;                                     \
    }                                                                       \
  }

  LOADR(0);
  WRITELDS(0);
  __syncthreads();
  int cur = 0;
  for (int t = 0; t < 8; ++t) {
    if (t < 7) LOADR((t + 1) * 64);
#pragma unroll
    for (int kk = 0; kk < 2; ++kk) {
      short8 a_h[2], a_l[2], b_h[2], b_l[2];
      const int kbyte = kk * 64 + ((lane >> 4) << 4);
#pragma unroll
      for (int fm = 0; fm < 2; ++fm) {
        const int row = wm + fm * 16 + (lane & 15);
        const int off = (row * 128 + (kbyte ^ ((row & 7) << 4))) >> 1;
        a_h[fm] = *(const short8*)&lA[cur][0][off];
        a_l[fm] = *(const short8*)&lA[cur][1][off];
      }
#pragma unroll
      for (int fn = 0; fn < 2; ++fn) {
        const int nn = wn + fn * 16 + (lane & 15);
        const int off = (nn * 128 + (kbyte ^ ((nn & 7) << 4))) >> 1;
        b_h[fn] = *(const short8*)&lB[cur][0][off];
        b_l[fn] = *(const short8*)&lB[cur][1][off];
      }
#pragma unroll
      for (int fm = 0; fm < 2; ++fm)
#pragma unroll
        for (int fn = 0; fn < 2; ++fn) {
          acc[fm][fn] = __builtin_amdgcn_mfma_f32_16x16x32_bf16(
              a_h[fm], b_h[fn], acc[fm][fn], 0, 0, 0);
          acc[fm][fn] = __builtin_amdgcn_mfma_f32_16x16x32_bf16(
              a_h[fm], b_l[fn], acc[fm][fn], 0, 0, 0);
          acc[fm][fn] = __builtin_amdgcn_mfma_f32_16x16x32_bf16(
              a_l[fm], b_h[fn], acc[fm][fn], 0, 0, 0);
        }
    }
    if (t < 7) WRITELDS(cur ^ 1);
    __syncthreads();
    cur ^= 1;
  }
#undef LOADR
#undef WRITELDS

  // ---- epilogue A: transpose head-tile via LDS, store bf16-RNE gT ----
  float* T = (float*)lA;  // [64 cols][132 rows-padded]
#pragma unroll
  for (int fm = 0; fm < 2; ++fm)
#pragma unroll
    for (int fn = 0; fn < 2; ++fn)
#pragma unroll
      for (int r = 0; r < 4; ++r) {
        const int col = wn + fn * 16 + (lane & 15);
        const int rl = wm + fm * 16 + ((lane >> 4) << 2) + r;
        T[col * 132 + rl] = acc[fm][fn][r];
      }
  __syncthreads();
  {
    const int b = row0 >> 11;
    const int n0 = row0 & (N_ - 1);
    const int d = tid >> 3;
    const int nc = (tid & 7) * 16;
    const size_t gb = ((size_t)((b * H_ + blockIdx.y) * 64 + d)) * N_ + n0 + nc;
#pragma unroll
    for (int half = 0; half < 2; ++half) {
      short8 hv;
#pragma unroll
      for (int u = 0; u < 8; ++u)
        hv[u] = (short)bf16_rne(T[d * 132 + nc + half * 8 + u]);
      *(short8*)&gT[gb + half * 8] = hv;
    }
  }

  // ---- epilogue B: fused sl/sr + exp tables ----
  const float al0 = aw[wn + (lane & 15)];
  const float al1 = aw[wn + 16 + (lane & 15)];
  const float ar0 = aw[DH + wn + (lane & 15)];
  const float ar1 = aw[DH + wn + 16 + (lane & 15)];
#pragma unroll
  for (int fm = 0; fm < 2; ++fm)
#pragma unroll
    for (int r = 0; r < 4; ++r) {
      float vsl = acc[fm][0][r] * al0 + acc[fm][1][r] * al1;
      float vsr = acc[fm][0][r] * ar0 + acc[fm][1][r] * ar1;
#pragma unroll
      for (int off = 1; off < 16; off <<= 1) {
        vsl += __shfl_xor(vsl, off, 64);
        vsr += __shfl_xor(vsr, off, 64);
      }
      if ((lane & 15) == 0) {
        const int rr = wm + fm * 16 + ((lane >> 4) << 2) + r;
        slp[wn >> 5][rr] = vsl;
        srp[wn >> 5][rr] = vsr;
      }
    }
  __syncthreads();
  if (tid < 128) {
    const int grow = row0 + tid;
    const int b = grow >> 11, n = grow & (N_ - 1);
    const int h = blockIdx.y;
    const int idx = (b * H_ + h) * N_ + n;
    const float srv = srp[0][tid] + srp[1][tid];
    sl[idx] = slp[0][tid] + slp[1][tid];
    sr[idx] = srv;
    Bn[idx] = exp2f(srv * LOG2E);
    Dn[idx] = exp2f(srv * (SLOPE * LOG2E));
  }
}

// K2: flash attention, rank-1 scores. P = max(Ai*Bj, Ci*Dj) — EXACT identity
// for exp(lrelu(sl+sr)-M): the lrelu branch always picks the larger exponent.
// Single bf16-RNE V (8 PV MFMA + 2 Z MFMA per iter, was 18). 256 thr (4
// waves x 16 rows), grid (16 bh, 32 it). Swizzled single-hi LDS, dbuf.
__global__ __launch_bounds__(256) void k_attn(const ushort_t* __restrict__ gT,
                                              const float* __restrict__ sl,
                                              const float* __restrict__ sr,
                                              const float* __restrict__ Bn,
                                              const float* __restrict__ Dn,
                                              float* __restrict__ out) {
  __shared__ ushort_t ghi[2][64 * 64];  // 8KB per buf
  __shared__ float wred[4];
  const int tid = threadIdx.x;
  const int lane = tid & 63;
  const int wave = tid >> 6;
  const int bh = blockIdx.x;
  const int b = bh >> 3, h = bh & 7;
  const int i0 = blockIdx.y * 64 + wave * 16;
  const int row_l = lane & 15;
  const int kg = lane >> 4;
  const int sd = tid >> 2;         // staging d 0..63
  const int sjb = (tid & 3) * 16;  // staging j0 (16 ushorts = 2 short8)

  // prologue: srmax for this bh
  float mx = -1e30f;
  for (int q = tid; q < N_; q += 256) mx = fmaxf(mx, sr[bh * N_ + q]);
#pragma unroll
  for (int off = 32; off > 0; off >>= 1) mx = fmaxf(mx, __shfl_xor(mx, off, 64));
  if (lane == 0) wred[wave] = mx;
  __syncthreads();
  mx = fmaxf(fmaxf(wred[0], wred[1]), fmaxf(wred[2], wred[3]));

  const float sli = sl[bh * N_ + i0 + row_l];
  const float pre = sli + mx;
  const float Mi = fmaxf(pre, SLOPE * pre);  // exact row max of e
  const float Ai = exp2f(fmaf(sli, LOG2E, -Mi * LOG2E));
  const float Ci = exp2f(fmaf(sli, SLOPE * LOG2E, -Mi * LOG2E));

  int ridx[4][2];
#pragma unroll
  for (int gg = 0; gg < 4; ++gg) {
    const int d = gg * 16 + row_l;
#pragma unroll
    for (int kk = 0; kk < 2; ++kk) {
      const int j0r = kk * 32 + kg * 8;
      ridx[gg][kk] = d * 64 + (j0r ^ ((d & 7) << 3));
    }
  }
  const short8 ones = {0x3F80, 0x3F80, 0x3F80, 0x3F80,
                       0x3F80, 0x3F80, 0x3F80, 0x3F80};

  const ushort_t* gH = gT + ((size_t)bh * 64 + sd) * N_ + sjb;
  const float* Bp0 = Bn + bh * N_ + kg * 8;
  const float* Bp1 = Bn + bh * N_ + 32 + kg * 8;
  const float* Dp0 = Dn + bh * N_ + kg * 8;
  const float* Dp1 = Dn + bh * N_ + 32 + kg * 8;

  f32x4 O[4] = {};
  f32x4 Zacc = {};
  short8 sh0, sh1;

#define ALOAD(jb)                                                           \
  {                                                                         \
    sh0 = *(const short8*)&gH[jb];                                          \
    sh1 = *(const short8*)&gH[(jb) + 8];                                    \
  }
#define AWRITE(buf)                                                         \
  {                                                                         \
    const int base_ = sd * 64;                                              \
    const int sw_ = (sd & 7) << 3;                                          \
    *(short8*)&ghi[buf][base_ + (sjb ^ sw_)] = sh0;                         \
    *(short8*)&ghi[buf][base_ + ((sjb + 8) ^ sw_)] = sh1;                   \
  }

  ALOAD(0);
  AWRITE(0);
  __syncthreads();
  int cur = 0;
  for (int t = 0; t < 32; ++t) {
    const int jb = t * 64;
    if (t < 31) ALOAD(jb + 64);
    // P = max(Ai*Bj, Ci*Dj), bf16 RNE — 3 VALU + cvt per element
    short8 a[2];
    {
      const float4 b0 = *(const float4*)&Bp0[jb];
      const float4 b1 = *(const float4*)&Bp0[jb + 4];
      const float4 b2 = *(const float4*)&Bp1[jb];
      const float4 b3 = *(const float4*)&Bp1[jb + 4];
      const float4 d0 = *(const float4*)&Dp0[jb];
      const float4 d1 = *(const float4*)&Dp0[jb + 4];
      const float4 d2 = *(const float4*)&Dp1[jb];
      const float4 d3 = *(const float4*)&Dp1[jb + 4];
      const float bs0[8] = {b0.x, b0.y, b0.z, b0.w, b1.x, b1.y, b1.z, b1.w};
      const float ds0[8] = {d0.x, d0.y, d0.z, d0.w, d1.x, d1.y, d1.z, d1.w};
      const float bs1[8] = {b2.x, b2.y, b2.z, b2.w, b3.x, b3.y, b3.z, b3.w};
      const float ds1[8] = {d2.x, d2.y, d2.z, d2.w, d3.x, d3.y, d3.z, d3.w};
#pragma unroll
      for (int u = 0; u < 8; ++u) {
        a[0][u] = (short)bf16_rne(fmaxf(Ai * bs0[u], Ci * ds0[u]));
        a[1][u] = (short)bf16_rne(fmaxf(Ai * bs1[u], Ci * ds1[u]));
      }
    }
    Zacc = __builtin_amdgcn_mfma_f32_16x16x32_bf16(a[0], ones, Zacc, 0, 0, 0);
    Zacc = __builtin_amdgcn_mfma_f32_16x16x32_bf16(a[1], ones, Zacc, 0, 0, 0);
#pragma unroll
    for (int gg = 0; gg < 4; ++gg)
#pragma unroll
      for (int kk = 0; kk < 2; ++kk) {
        const short8 b_h = *(const short8*)&ghi[cur][ridx[gg][kk]];
        O[gg] = __builtin_amdgcn_mfma_f32_16x16x32_bf16(a[kk], b_h, O[gg], 0, 0, 0);
      }
    if (t < 31) AWRITE(cur ^ 1);
    __syncthreads();
    cur ^= 1;
  }
#undef ALOAD
#undef AWRITE
  // epilogue: O / Z (Zacc shares the C-fragment row layout — no shuffles)
#pragma unroll
  for (int gg = 0; gg < 4; ++gg)
#pragma unroll
    for (int rr = 0; rr < 4; ++rr) {
      const int row = i0 + kg * 4 + rr;
      const int col = h * DH + gg * 16 + row_l;
      out[(b * N_ + row) * HD + col] = O[gg][rr] / Zacc[rr];
    }
}

extern "C" void kernel_launch(void* const* d_in, const int* in_sizes, int n_in,
                              void* d_out, int out_size, void* d_ws, size_t ws_size,
                              hipStream_t stream) {
  const float* f = (const float*)d_in[0];
  // d_in[1] = adj_mat (all ones, unused by reference math)
  const float* W = (const float*)d_in[2];
  const float* aw = (const float*)d_in[3];
  float* out = (float*)d_out;

  ushort_t* gT = (ushort_t*)d_ws;            // [16 bh][64 d][2048 n] bf16 RNE
  float* sl = (float*)(gT + 16 * 64 * N_);   // [bh][n]
  float* sr = sl + B_ * N_ * H_;
  float* Bn = sr + B_ * N_ * H_;             // exp(sr)
  float* Dn = Bn + B_ * N_ * H_;             // exp(0.2*sr)

  hipLaunchKernelGGL(k_gemm_fused, dim3((B_ * N_) / 128, HD / 64), dim3(512), 0, stream,
                     f, W, aw, gT, sl, sr, Bn, Dn);
  hipLaunchKernelGGL(k_attn, dim3(B_ * H_, N_ / 64), dim3(256), 0, stream,
                     gT, sl, sr, Bn, Dn, out);
}